// Round 11
// baseline (849.576 us; speedup 1.0000x reference)
//
#include <hip/hip_runtime.h>
#include <math.h>

#define N_NODES 100000
#define LN_EPS 1e-5f
#define BK_SH 7   // 128 nodes per bucket

typedef __attribute__((ext_vector_type(8))) short bf16x8;
typedef __attribute__((ext_vector_type(4))) float f32x4;

__device__ __forceinline__ unsigned short f2bf(float f) {
    unsigned int u = __float_as_uint(f);
    return (unsigned short)((u + 0x7FFFu + ((u >> 16) & 1u)) >> 16);
}
__device__ __forceinline__ float bf2f(unsigned short u) {
    return __uint_as_float(((unsigned int)u) << 16);
}

// ---------------- small utility kernels ----------------
__global__ void zero_int(int* __restrict__ p, int n) {
    int i = blockIdx.x * blockDim.x + threadIdx.x;
    if (i < n) p[i] = 0;
}

__global__ void hist_dst(const int* __restrict__ dst, int* __restrict__ deg, int E) {
    int e = blockIdx.x * blockDim.x + threadIdx.x;
    if (e < E) atomicAdd(&deg[dst[e]], 1);
}

// exclusive scan (256/block) + fused dinv = rsqrt(deg+1)
__global__ void scan_block_dinv(const int* __restrict__ in, int* __restrict__ out,
                                int* __restrict__ bsums, float* __restrict__ dinv, int n) {
    __shared__ int s[256];
    int i = blockIdx.x * 256 + threadIdx.x;
    int v = (i < n) ? in[i] : 0;
    s[threadIdx.x] = v;
    __syncthreads();
    for (int off = 1; off < 256; off <<= 1) {
        int t = ((int)threadIdx.x >= off) ? s[threadIdx.x - off] : 0;
        __syncthreads();
        s[threadIdx.x] += t;
        __syncthreads();
    }
    if (i < n) {
        out[i] = s[threadIdx.x] - v;  // exclusive
        dinv[i] = rsqrtf((float)v + 1.f);
    }
    if (threadIdx.x == 255) bsums[blockIdx.x] = s[255];
}

// parallel exclusive scan of block sums (nb <= 512) + set offsets[N]=E
__global__ void scan_sums_p(int* __restrict__ bsums, int nb, int* __restrict__ off_end, int Ev) {
    __shared__ int s[512];
    int i = threadIdx.x;
    int v = (i < nb) ? bsums[i] : 0;
    s[i] = v;
    __syncthreads();
    for (int off = 1; off < 512; off <<= 1) {
        int t = (i >= off) ? s[i - off] : 0;
        __syncthreads();
        s[i] += t;
        __syncthreads();
    }
    if (i < nb) bsums[i] = s[i] - v;
    if (i == 0) *off_end = Ev;
}

// finalize offsets, init per-node cursor, init per-bucket cursor
__global__ void scan_add_copy(int* __restrict__ out, int* __restrict__ cursor,
                              int* __restrict__ bcur, const int* __restrict__ bsums, int n) {
    int i = blockIdx.x * 256 + threadIdx.x;
    if (i < n) {
        int v = out[i] + bsums[blockIdx.x];
        out[i] = v;
        cursor[i] = v;
        if ((i & ((1 << BK_SH) - 1)) == 0) bcur[i >> BK_SH] = v;
    }
}

// pass A: radix-partition edges by dst bucket; writes L2-combinable (782 tails)
__global__ void part_edges(const int* __restrict__ src, const int* __restrict__ dst,
                           int* __restrict__ bcur, int2* __restrict__ part, int E) {
    int e = blockIdx.x * blockDim.x + threadIdx.x;
    if (e < E) {
        int d = dst[e];
        int pos = atomicAdd(&bcur[d >> BK_SH], 1);
        part[pos] = make_int2(src[e], d);
    }
}

// pass B: bucket-localized scatter into csr (writes stay in an ~8KB L2 window)
__global__ void fill_csr2(const int2* __restrict__ part, int* __restrict__ cursor,
                          int* __restrict__ csr_src, int E) {
    int e = blockIdx.x * blockDim.x + threadIdx.x;
    if (e < E) {
        int2 p = part[e];
        int pos = atomicAdd(&cursor[p.y], 1);
        csr_src[pos] = p.x;
    }
}

// ---------------- MFMA bf16 gemm: Y = X[n,K] @ W[K,OUT] (+bias, +LN+ELU) ----------------
template <int K, int OUT, bool LN, bool BIAS, bool AF32, bool OF32>
__launch_bounds__(256)
__global__ void mfma_gemm(const void* __restrict__ Xv, const float* __restrict__ W,
                          const float* __restrict__ bias, const float* __restrict__ gamma,
                          const float* __restrict__ beta, void* __restrict__ Yv, int n) {
    constexpr int T  = OUT / 16;
    constexpr int KP = K + 8;

    __shared__ __align__(16) unsigned short sWT[OUT * KP];  // W^T bf16
    for (int i = threadIdx.x; i < K * OUT; i += 256) {
        int k = i / OUT, o = i - k * OUT;
        sWT[o * KP + k] = f2bf(W[i]);
    }
    __syncthreads();

    int wv = threadIdx.x >> 6, lane = threadIdx.x & 63;
    int quad = lane >> 4, l16 = lane & 15;
    int m0 = (blockIdx.x * 4 + wv) * 16;
    int rowc = min(m0 + l16, n - 1);

    f32x4 acc[T];
#pragma unroll
    for (int t = 0; t < T; ++t) acc[t] = (f32x4){0.f, 0.f, 0.f, 0.f};

#pragma unroll
    for (int s = 0; s < K / 32; ++s) {
        int koff = s * 32 + quad * 8;
        bf16x8 af;
        if (AF32) {
            const float4* X4 = (const float4*)Xv;
            size_t base = ((size_t)rowc * K + koff) >> 2;
            float4 a0 = X4[base];
            float4 a1 = X4[base + 1];
            af[0] = (short)f2bf(a0.x); af[1] = (short)f2bf(a0.y);
            af[2] = (short)f2bf(a0.z); af[3] = (short)f2bf(a0.w);
            af[4] = (short)f2bf(a1.x); af[5] = (short)f2bf(a1.y);
            af[6] = (short)f2bf(a1.z); af[7] = (short)f2bf(a1.w);
        } else {
            const unsigned short* Xb = (const unsigned short*)Xv;
            af = *(const bf16x8*)(Xb + (size_t)rowc * K + koff);
        }
#pragma unroll
        for (int t = 0; t < T; ++t) {
            const bf16x8 bfrag = *(const bf16x8*)&sWT[(t * 16 + l16) * KP + koff];
            acc[t] = __builtin_amdgcn_mfma_f32_16x16x32_bf16(af, bfrag, acc[t], 0, 0, 0);
        }
    }

    float bj[T], gj[T], btj[T];
#pragma unroll
    for (int t = 0; t < T; ++t) {
        int c = t * 16 + l16;
        bj[t]  = BIAS ? bias[c] : 0.f;
        gj[t]  = LN ? gamma[c] : 1.f;
        btj[t] = LN ? beta[c] : 0.f;
    }

    float* Yf = (float*)Yv;
    unsigned short* Yb = (unsigned short*)Yv;

    if (LN) {
        float s[4] = {0.f, 0.f, 0.f, 0.f}, sq[4] = {0.f, 0.f, 0.f, 0.f};
#pragma unroll
        for (int t = 0; t < T; ++t)
#pragma unroll
            for (int r = 0; r < 4; ++r) {
                float v = acc[t][r] + bj[t];
                s[r] += v;
                sq[r] += v * v;
            }
#pragma unroll
        for (int off = 1; off < 16; off <<= 1)
#pragma unroll
            for (int r = 0; r < 4; ++r) {
                s[r] += __shfl_xor(s[r], off, 64);
                sq[r] += __shfl_xor(sq[r], off, 64);
            }
        float mu[4], rs[4];
#pragma unroll
        for (int r = 0; r < 4; ++r) {
            mu[r] = s[r] / OUT;
            float var = sq[r] / OUT - mu[r] * mu[r];
            rs[r] = rsqrtf(var + LN_EPS);
        }
#pragma unroll
        for (int r = 0; r < 4; ++r) {
            int rowg = m0 + quad * 4 + r;
            if (rowg < n) {
#pragma unroll
                for (int t = 0; t < T; ++t) {
                    float y = (acc[t][r] + bj[t] - mu[r]) * rs[r] * gj[t] + btj[t];
                    y = y > 0.f ? y : expm1f(y);
                    size_t idx = (size_t)rowg * OUT + t * 16 + l16;
                    if (OF32) Yf[idx] = y; else Yb[idx] = f2bf(y);
                }
            }
        }
    } else {
#pragma unroll
        for (int r = 0; r < 4; ++r) {
            int rowg = m0 + quad * 4 + r;
            if (rowg < n) {
#pragma unroll
                for (int t = 0; t < T; ++t) {
                    float y = acc[t][r] + bj[t];
                    size_t idx = (size_t)rowg * OUT + t * 16 + l16;
                    if (OF32) Yf[idx] = y; else Yb[idx] = f2bf(y);
                }
            }
        }
    }
}

// ---------------- fused gather v2: 4 edges per wave-load (ushort4/lane) ----------------
template <bool LN>
__global__ void gather64(const unsigned short* __restrict__ xw, const int* __restrict__ offsets,
                         const int* __restrict__ csr_src, const float* __restrict__ dinv,
                         const float* __restrict__ bias, const float* __restrict__ gamma,
                         const float* __restrict__ beta, unsigned short* __restrict__ out, int n) {
    int wave = threadIdx.x >> 6;
    int lane = threadIdx.x & 63;
    int node = blockIdx.x * (blockDim.x >> 6) + wave;
    if (node >= n) return;
    int beg = offsets[node], end = offsets[node + 1];
    int quad = lane >> 4, q16 = lane & 15;
    int c0 = q16 * 4;

    float a0 = 0.f, a1 = 0.f, a2 = 0.f, a3 = 0.f;
    for (int base = beg; base < end; base += 64) {
        int m = min(64, end - base);
        int myS = (lane < m) ? csr_src[base + lane] : 0;
        float myN = (lane < m) ? dinv[myS] : 0.f;  // 0-weight for pad lanes
#pragma unroll 4
        for (int j4 = 0; j4 < m; j4 += 4) {
            int e = j4 + quad;
            int s = __shfl(myS, e, 64);
            float nm = __shfl(myN, e, 64);
            ushort4 r = *(const ushort4*)(xw + (size_t)s * 64 + c0);
            a0 += bf2f(r.x) * nm;
            a1 += bf2f(r.y) * nm;
            a2 += bf2f(r.z) * nm;
            a3 += bf2f(r.w) * nm;
        }
    }
    a0 += __shfl_xor(a0, 16, 64); a0 += __shfl_xor(a0, 32, 64);
    a1 += __shfl_xor(a1, 16, 64); a1 += __shfl_xor(a1, 32, 64);
    a2 += __shfl_xor(a2, 16, 64); a2 += __shfl_xor(a2, 32, 64);
    a3 += __shfl_xor(a3, 16, 64); a3 += __shfl_xor(a3, 32, 64);

    float dd = dinv[node];
    ushort4 sr = *(const ushort4*)(xw + (size_t)node * 64 + c0);
    float y0 = a0 * dd + bf2f(sr.x) * dd * dd;
    float y1 = a1 * dd + bf2f(sr.y) * dd * dd;
    float y2 = a2 * dd + bf2f(sr.z) * dd * dd;
    float y3 = a3 * dd + bf2f(sr.w) * dd * dd;

    if (!LN) {
        if (quad == 0) {
            ushort4 o;
            o.x = f2bf(y0); o.y = f2bf(y1); o.z = f2bf(y2); o.w = f2bf(y3);
            *(ushort4*)(out + (size_t)node * 64 + c0) = o;
        }
        return;
    }
    float4 bv = *(const float4*)(bias + c0);
    float4 gv = *(const float4*)(gamma + c0);
    float4 tv = *(const float4*)(beta + c0);
    y0 += bv.x; y1 += bv.y; y2 += bv.z; y3 += bv.w;
    float s = y0 + y1 + y2 + y3;
    float sq = y0 * y0 + y1 * y1 + y2 * y2 + y3 * y3;
#pragma unroll
    for (int off = 1; off < 16; off <<= 1) {
        s += __shfl_xor(s, off, 64);
        sq += __shfl_xor(sq, off, 64);
    }
    float mu = s / 64.f;
    float var = sq / 64.f - mu * mu;
    float rs = rsqrtf(var + LN_EPS);
    float z0 = (y0 - mu) * rs * gv.x + tv.x; z0 = z0 > 0.f ? z0 : expm1f(z0);
    float z1 = (y1 - mu) * rs * gv.y + tv.y; z1 = z1 > 0.f ? z1 : expm1f(z1);
    float z2 = (y2 - mu) * rs * gv.z + tv.z; z2 = z2 > 0.f ? z2 : expm1f(z2);
    float z3 = (y3 - mu) * rs * gv.w + tv.w; z3 = z3 > 0.f ? z3 : expm1f(z3);
    if (quad == 0) {
        ushort4 o;
        o.x = f2bf(z0); o.y = f2bf(z1); o.z = f2bf(z2); o.w = f2bf(z3);
        *(ushort4*)(out + (size_t)node * 64 + c0) = o;
    }
}

extern "C" void kernel_launch(void* const* d_in, const int* in_sizes, int n_in,
                              void* d_out, int out_size, void* d_ws, size_t ws_size,
                              hipStream_t stream) {
    const float* x  = (const float*)d_in[0];
    const int* ei   = (const int*)d_in[1];
    const float* W1 = (const float*)d_in[2];
    const float* b1 = (const float*)d_in[3];
    const float* g1 = (const float*)d_in[4];
    const float* be1= (const float*)d_in[5];
    const float* W2 = (const float*)d_in[6];
    const float* b2 = (const float*)d_in[7];
    const float* g2 = (const float*)d_in[8];
    const float* be2= (const float*)d_in[9];
    const float* W3 = (const float*)d_in[10];
    const float* b3 = (const float*)d_in[11];
    const float* g3 = (const float*)d_in[12];
    const float* be3= (const float*)d_in[13];
    const float* lw1= (const float*)d_in[14];
    const float* lb1= (const float*)d_in[15];
    const float* g4 = (const float*)d_in[16];
    const float* be4= (const float*)d_in[17];
    const float* lw2= (const float*)d_in[18];
    const float* lb2= (const float*)d_in[19];
    float* out = (float*)d_out;

    const int E = in_sizes[1] / 2;
    const int* src = ei;
    const int* dst = ei + E;
    const int N = N_NODES;
    const int NBK = (N + (1 << BK_SH) - 1) >> BK_SH;  // 782 buckets

    // workspace layout (intermediates in bf16)
    unsigned short* bufA = (unsigned short*)d_ws;       // N*128 bf16
    unsigned short* bufB = bufA + (size_t)N * 128;      // N*128 bf16
    float* dinv    = (float*)(bufB + (size_t)N * 128);  // N f32
    int*   deg     = (int*)(dinv + N);                  // N
    int*   offsets = deg + N;                           // N+1
    int*   cursor  = offsets + N + 1;                   // N
    int*   csr     = cursor + N;                        // E
    int*   bsums   = csr + E;                           // ceil(N/256)
    int*   bcur    = bsums + 512;                       // NBK
    int2*  part    = (int2*)(bcur + NBK + 2);           // E pairs

    auto cdiv = [](long long a, long long b) { return (int)((a + b - 1) / b); };
    const int NB = cdiv(N, 256);
    const int GB = cdiv(N, 64);  // mfma gemm grid (64 rows/block)

    // ---- build CSR (dst-sorted) + dinv, radix-partitioned scatter ----
    zero_int<<<NB, 256, 0, stream>>>(deg, N);
    hist_dst<<<cdiv(E, 256), 256, 0, stream>>>(dst, deg, E);
    scan_block_dinv<<<NB, 256, 0, stream>>>(deg, offsets, bsums, dinv, N);
    scan_sums_p<<<1, 512, 0, stream>>>(bsums, NB, offsets + N, E);
    scan_add_copy<<<NB, 256, 0, stream>>>(offsets, cursor, bcur, bsums, N);
    part_edges<<<cdiv(E, 256), 256, 0, stream>>>(src, dst, bcur, part, E);
    fill_csr2<<<cdiv(E, 256), 256, 0, stream>>>(part, cursor, csr, E);

    // ---- Layer 1: xw1 = x @ W1 (128->64, fp32 in); h1 = LN_ELU(gather + b1) ----
    mfma_gemm<128, 64, false, false, true, false><<<GB, 256, 0, stream>>>(
        x, W1, nullptr, nullptr, nullptr, bufA, N);
    gather64<true><<<cdiv(N, 4), 256, 0, stream>>>(bufA, offsets, csr, dinv, b1, g1, be1, bufB, N);

    // ---- Layer 2 (aggregate-first): a2 = gather(h1); h2 = LN_ELU(a2 @ W2 + b2) ----
    gather64<false><<<cdiv(N, 4), 256, 0, stream>>>(bufB, offsets, csr, dinv, nullptr, nullptr, nullptr, bufA, N);
    mfma_gemm<64, 128, true, true, false, false><<<GB, 256, 0, stream>>>(
        bufA, W2, b2, g2, be2, bufB, N);

    // ---- Layer 3: xw3 = h2 @ W3 (128->64); h3 = LN_ELU(gather + b3) ----
    mfma_gemm<128, 64, false, false, false, false><<<GB, 256, 0, stream>>>(
        bufB, W3, nullptr, nullptr, nullptr, bufA, N);
    gather64<true><<<cdiv(N, 4), 256, 0, stream>>>(bufA, offsets, csr, dinv, b3, g3, be3, bufB, N);

    // ---- lin1: t = LN_ELU(h3 @ lw1 + lb1) (64->32) ----
    mfma_gemm<64, 32, true, true, false, false><<<GB, 256, 0, stream>>>(
        bufB, lw1, lb1, g4, be4, bufA, N);

    // ---- lin2: out = t @ lw2 + lb2 (32->32, fp32 out) ----
    mfma_gemm<32, 32, false, true, false, true><<<GB, 256, 0, stream>>>(
        bufA, lw2, lb2, nullptr, nullptr, out, N);
}

// Round 12
// 490.589 us; speedup vs baseline: 1.7317x; 1.7317x over previous
//
#include <hip/hip_runtime.h>
#include <math.h>

#define N_NODES 100000
#define LN_EPS 1e-5f

typedef __attribute__((ext_vector_type(8))) short bf16x8;
typedef __attribute__((ext_vector_type(4))) float f32x4;

__device__ __forceinline__ unsigned short f2bf(float f) {
    unsigned int u = __float_as_uint(f);
    return (unsigned short)((u + 0x7FFFu + ((u >> 16) & 1u)) >> 16);
}
__device__ __forceinline__ float bf2f(unsigned short u) {
    return __uint_as_float(((unsigned int)u) << 16);
}

// ---------------- small utility kernels ----------------
__global__ void zero_int(int* __restrict__ p, int n) {
    int i = blockIdx.x * blockDim.x + threadIdx.x;
    if (i < n) p[i] = 0;
}

__global__ void hist_dst(const int* __restrict__ dst, int* __restrict__ deg, int E) {
    int e = blockIdx.x * blockDim.x + threadIdx.x;
    if (e < E) atomicAdd(&deg[dst[e]], 1);
}

// exclusive scan (256/block) + fused dinv = rsqrt(deg+1)
__global__ void scan_block_dinv(const int* __restrict__ in, int* __restrict__ out,
                                int* __restrict__ bsums, float* __restrict__ dinv, int n) {
    __shared__ int s[256];
    int i = blockIdx.x * 256 + threadIdx.x;
    int v = (i < n) ? in[i] : 0;
    s[threadIdx.x] = v;
    __syncthreads();
    for (int off = 1; off < 256; off <<= 1) {
        int t = ((int)threadIdx.x >= off) ? s[threadIdx.x - off] : 0;
        __syncthreads();
        s[threadIdx.x] += t;
        __syncthreads();
    }
    if (i < n) {
        out[i] = s[threadIdx.x] - v;  // exclusive
        dinv[i] = rsqrtf((float)v + 1.f);
    }
    if (threadIdx.x == 255) bsums[blockIdx.x] = s[255];
}

// parallel exclusive scan of block sums (nb <= 512) + set offsets[N]=E
__global__ void scan_sums_p(int* __restrict__ bsums, int nb, int* __restrict__ off_end, int Ev) {
    __shared__ int s[512];
    int i = threadIdx.x;
    int v = (i < nb) ? bsums[i] : 0;
    s[i] = v;
    __syncthreads();
    for (int off = 1; off < 512; off <<= 1) {
        int t = (i >= off) ? s[i - off] : 0;
        __syncthreads();
        s[i] += t;
        __syncthreads();
    }
    if (i < nb) bsums[i] = s[i] - v;
    if (i == 0) *off_end = Ev;
}

// finalize offsets AND init cursor=offsets
__global__ void scan_add_copy(int* __restrict__ out, int* __restrict__ cursor,
                              const int* __restrict__ bsums, int n) {
    int i = blockIdx.x * 256 + threadIdx.x;
    if (i < n) {
        int v = out[i] + bsums[blockIdx.x];
        out[i] = v;
        cursor[i] = v;
    }
}

// XCD-pinned CSR fill: 8x blocks; block handles chunk (b>>3), but only edges
// whose dst region (d/12500) == (b&7). With blockIdx%8 ~ XCD, each csr region
// (~800KB < 4MB L2/XCD) is written by ONE XCD -> no cross-XCD line ping-pong
// (R10 fill_csr: 105MB WRITE for 6.4MB csr). Reads are 8x but L2/L3-served.
__global__ void fill_csr_xcd(const int* __restrict__ src, const int* __restrict__ dst,
                             int* __restrict__ cursor, int* __restrict__ csr_src, int E) {
    int xcd = blockIdx.x & 7;
    int e = (blockIdx.x >> 3) * blockDim.x + threadIdx.x;
    if (e >= E) return;
    int d = dst[e];
    if (d / 12500 != xcd) return;
    int pos = atomicAdd(&cursor[d], 1);
    csr_src[pos] = src[e];
}

// ---------------- MFMA bf16 gemm: Y = X[n,K] @ W[K,OUT] (+bias, +LN+ELU) ----------------
template <int K, int OUT, bool LN, bool BIAS, bool AF32, bool OF32>
__launch_bounds__(256)
__global__ void mfma_gemm(const void* __restrict__ Xv, const float* __restrict__ W,
                          const float* __restrict__ bias, const float* __restrict__ gamma,
                          const float* __restrict__ beta, void* __restrict__ Yv, int n) {
    constexpr int T  = OUT / 16;
    constexpr int KP = K + 8;

    __shared__ __align__(16) unsigned short sWT[OUT * KP];  // W^T bf16
    for (int i = threadIdx.x; i < K * OUT; i += 256) {
        int k = i / OUT, o = i - k * OUT;
        sWT[o * KP + k] = f2bf(W[i]);
    }
    __syncthreads();

    int wv = threadIdx.x >> 6, lane = threadIdx.x & 63;
    int quad = lane >> 4, l16 = lane & 15;
    int m0 = (blockIdx.x * 4 + wv) * 16;
    int rowc = min(m0 + l16, n - 1);

    f32x4 acc[T];
#pragma unroll
    for (int t = 0; t < T; ++t) acc[t] = (f32x4){0.f, 0.f, 0.f, 0.f};

#pragma unroll
    for (int s = 0; s < K / 32; ++s) {
        int koff = s * 32 + quad * 8;
        bf16x8 af;
        if (AF32) {
            const float4* X4 = (const float4*)Xv;
            size_t base = ((size_t)rowc * K + koff) >> 2;
            float4 a0 = X4[base];
            float4 a1 = X4[base + 1];
            af[0] = (short)f2bf(a0.x); af[1] = (short)f2bf(a0.y);
            af[2] = (short)f2bf(a0.z); af[3] = (short)f2bf(a0.w);
            af[4] = (short)f2bf(a1.x); af[5] = (short)f2bf(a1.y);
            af[6] = (short)f2bf(a1.z); af[7] = (short)f2bf(a1.w);
        } else {
            const unsigned short* Xb = (const unsigned short*)Xv;
            af = *(const bf16x8*)(Xb + (size_t)rowc * K + koff);
        }
#pragma unroll
        for (int t = 0; t < T; ++t) {
            const bf16x8 bfrag = *(const bf16x8*)&sWT[(t * 16 + l16) * KP + koff];
            acc[t] = __builtin_amdgcn_mfma_f32_16x16x32_bf16(af, bfrag, acc[t], 0, 0, 0);
        }
    }

    float bj[T], gj[T], btj[T];
#pragma unroll
    for (int t = 0; t < T; ++t) {
        int c = t * 16 + l16;
        bj[t]  = BIAS ? bias[c] : 0.f;
        gj[t]  = LN ? gamma[c] : 1.f;
        btj[t] = LN ? beta[c] : 0.f;
    }

    float* Yf = (float*)Yv;
    unsigned short* Yb = (unsigned short*)Yv;

    if (LN) {
        float s[4] = {0.f, 0.f, 0.f, 0.f}, sq[4] = {0.f, 0.f, 0.f, 0.f};
#pragma unroll
        for (int t = 0; t < T; ++t)
#pragma unroll
            for (int r = 0; r < 4; ++r) {
                float v = acc[t][r] + bj[t];
                s[r] += v;
                sq[r] += v * v;
            }
#pragma unroll
        for (int off = 1; off < 16; off <<= 1)
#pragma unroll
            for (int r = 0; r < 4; ++r) {
                s[r] += __shfl_xor(s[r], off, 64);
                sq[r] += __shfl_xor(sq[r], off, 64);
            }
        float mu[4], rs[4];
#pragma unroll
        for (int r = 0; r < 4; ++r) {
            mu[r] = s[r] / OUT;
            float var = sq[r] / OUT - mu[r] * mu[r];
            rs[r] = rsqrtf(var + LN_EPS);
        }
#pragma unroll
        for (int r = 0; r < 4; ++r) {
            int rowg = m0 + quad * 4 + r;
            if (rowg < n) {
#pragma unroll
                for (int t = 0; t < T; ++t) {
                    float y = (acc[t][r] + bj[t] - mu[r]) * rs[r] * gj[t] + btj[t];
                    y = y > 0.f ? y : expm1f(y);
                    size_t idx = (size_t)rowg * OUT + t * 16 + l16;
                    if (OF32) Yf[idx] = y; else Yb[idx] = f2bf(y);
                }
            }
        }
    } else {
#pragma unroll
        for (int r = 0; r < 4; ++r) {
            int rowg = m0 + quad * 4 + r;
            if (rowg < n) {
#pragma unroll
                for (int t = 0; t < T; ++t) {
                    float y = acc[t][r] + bj[t];
                    size_t idx = (size_t)rowg * OUT + t * 16 + l16;
                    if (OF32) Yf[idx] = y; else Yb[idx] = f2bf(y);
                }
            }
        }
    }
}

// ---------------- fused gather v2: 4 edges per wave-load (ushort4/lane) ----------------
template <bool LN>
__global__ void gather64(const unsigned short* __restrict__ xw, const int* __restrict__ offsets,
                         const int* __restrict__ csr_src, const float* __restrict__ dinv,
                         const float* __restrict__ bias, const float* __restrict__ gamma,
                         const float* __restrict__ beta, unsigned short* __restrict__ out, int n) {
    int wave = threadIdx.x >> 6;
    int lane = threadIdx.x & 63;
    int node = blockIdx.x * (blockDim.x >> 6) + wave;
    if (node >= n) return;
    int beg = offsets[node], end = offsets[node + 1];
    int quad = lane >> 4, q16 = lane & 15;
    int c0 = q16 * 4;

    float a0 = 0.f, a1 = 0.f, a2 = 0.f, a3 = 0.f;
    for (int base = beg; base < end; base += 64) {
        int m = min(64, end - base);
        int myS = (lane < m) ? csr_src[base + lane] : 0;
        float myN = (lane < m) ? dinv[myS] : 0.f;  // 0-weight for pad lanes
#pragma unroll 4
        for (int j4 = 0; j4 < m; j4 += 4) {
            int e = j4 + quad;
            int s = __shfl(myS, e, 64);
            float nm = __shfl(myN, e, 64);
            ushort4 r = *(const ushort4*)(xw + (size_t)s * 64 + c0);
            a0 += bf2f(r.x) * nm;
            a1 += bf2f(r.y) * nm;
            a2 += bf2f(r.z) * nm;
            a3 += bf2f(r.w) * nm;
        }
    }
    a0 += __shfl_xor(a0, 16, 64); a0 += __shfl_xor(a0, 32, 64);
    a1 += __shfl_xor(a1, 16, 64); a1 += __shfl_xor(a1, 32, 64);
    a2 += __shfl_xor(a2, 16, 64); a2 += __shfl_xor(a2, 32, 64);
    a3 += __shfl_xor(a3, 16, 64); a3 += __shfl_xor(a3, 32, 64);

    float dd = dinv[node];
    ushort4 sr = *(const ushort4*)(xw + (size_t)node * 64 + c0);
    float y0 = a0 * dd + bf2f(sr.x) * dd * dd;
    float y1 = a1 * dd + bf2f(sr.y) * dd * dd;
    float y2 = a2 * dd + bf2f(sr.z) * dd * dd;
    float y3 = a3 * dd + bf2f(sr.w) * dd * dd;

    if (!LN) {
        if (quad == 0) {
            ushort4 o;
            o.x = f2bf(y0); o.y = f2bf(y1); o.z = f2bf(y2); o.w = f2bf(y3);
            *(ushort4*)(out + (size_t)node * 64 + c0) = o;
        }
        return;
    }
    float4 bv = *(const float4*)(bias + c0);
    float4 gv = *(const float4*)(gamma + c0);
    float4 tv = *(const float4*)(beta + c0);
    y0 += bv.x; y1 += bv.y; y2 += bv.z; y3 += bv.w;
    float s = y0 + y1 + y2 + y3;
    float sq = y0 * y0 + y1 * y1 + y2 * y2 + y3 * y3;
#pragma unroll
    for (int off = 1; off < 16; off <<= 1) {
        s += __shfl_xor(s, off, 64);
        sq += __shfl_xor(sq, off, 64);
    }
    float mu = s / 64.f;
    float var = sq / 64.f - mu * mu;
    float rs = rsqrtf(var + LN_EPS);
    float z0 = (y0 - mu) * rs * gv.x + tv.x; z0 = z0 > 0.f ? z0 : expm1f(z0);
    float z1 = (y1 - mu) * rs * gv.y + tv.y; z1 = z1 > 0.f ? z1 : expm1f(z1);
    float z2 = (y2 - mu) * rs * gv.z + tv.z; z2 = z2 > 0.f ? z2 : expm1f(z2);
    float z3 = (y3 - mu) * rs * gv.w + tv.w; z3 = z3 > 0.f ? z3 : expm1f(z3);
    if (quad == 0) {
        ushort4 o;
        o.x = f2bf(z0); o.y = f2bf(z1); o.z = f2bf(z2); o.w = f2bf(z3);
        *(ushort4*)(out + (size_t)node * 64 + c0) = o;
    }
}

extern "C" void kernel_launch(void* const* d_in, const int* in_sizes, int n_in,
                              void* d_out, int out_size, void* d_ws, size_t ws_size,
                              hipStream_t stream) {
    const float* x  = (const float*)d_in[0];
    const int* ei   = (const int*)d_in[1];
    const float* W1 = (const float*)d_in[2];
    const float* b1 = (const float*)d_in[3];
    const float* g1 = (const float*)d_in[4];
    const float* be1= (const float*)d_in[5];
    const float* W2 = (const float*)d_in[6];
    const float* b2 = (const float*)d_in[7];
    const float* g2 = (const float*)d_in[8];
    const float* be2= (const float*)d_in[9];
    const float* W3 = (const float*)d_in[10];
    const float* b3 = (const float*)d_in[11];
    const float* g3 = (const float*)d_in[12];
    const float* be3= (const float*)d_in[13];
    const float* lw1= (const float*)d_in[14];
    const float* lb1= (const float*)d_in[15];
    const float* g4 = (const float*)d_in[16];
    const float* be4= (const float*)d_in[17];
    const float* lw2= (const float*)d_in[18];
    const float* lb2= (const float*)d_in[19];
    float* out = (float*)d_out;

    const int E = in_sizes[1] / 2;
    const int* src = ei;
    const int* dst = ei + E;
    const int N = N_NODES;

    // workspace layout (intermediates in bf16)
    unsigned short* bufA = (unsigned short*)d_ws;       // N*128 bf16
    unsigned short* bufB = bufA + (size_t)N * 128;      // N*128 bf16
    float* dinv    = (float*)(bufB + (size_t)N * 128);  // N f32
    int*   deg     = (int*)(dinv + N);                  // N
    int*   offsets = deg + N;                           // N+1
    int*   cursor  = offsets + N + 1;                   // N
    int*   csr     = cursor + N;                        // E
    int*   bsums   = csr + E;                           // 512

    auto cdiv = [](long long a, long long b) { return (int)((a + b - 1) / b); };
    const int NB = cdiv(N, 256);
    const int GB = cdiv(N, 64);  // mfma gemm grid (64 rows/block)

    // ---- build CSR (dst-sorted) + dinv ----
    zero_int<<<NB, 256, 0, stream>>>(deg, N);
    hist_dst<<<cdiv(E, 256), 256, 0, stream>>>(dst, deg, E);
    scan_block_dinv<<<NB, 256, 0, stream>>>(deg, offsets, bsums, dinv, N);
    scan_sums_p<<<1, 512, 0, stream>>>(bsums, NB, offsets + N, E);
    scan_add_copy<<<NB, 256, 0, stream>>>(offsets, cursor, bsums, N);
    fill_csr_xcd<<<8 * cdiv(E, 256), 256, 0, stream>>>(src, dst, cursor, csr, E);

    // ---- Layer 1: xw1 = x @ W1 (128->64, fp32 in); h1 = LN_ELU(gather + b1) ----
    mfma_gemm<128, 64, false, false, true, false><<<GB, 256, 0, stream>>>(
        x, W1, nullptr, nullptr, nullptr, bufA, N);
    gather64<true><<<cdiv(N, 4), 256, 0, stream>>>(bufA, offsets, csr, dinv, b1, g1, be1, bufB, N);

    // ---- Layer 2 (aggregate-first): a2 = gather(h1); h2 = LN_ELU(a2 @ W2 + b2) ----
    gather64<false><<<cdiv(N, 4), 256, 0, stream>>>(bufB, offsets, csr, dinv, nullptr, nullptr, nullptr, bufA, N);
    mfma_gemm<64, 128, true, true, false, false><<<GB, 256, 0, stream>>>(
        bufA, W2, b2, g2, be2, bufB, N);

    // ---- Layer 3: xw3 = h2 @ W3 (128->64); h3 = LN_ELU(gather + b3) ----
    mfma_gemm<128, 64, false, false, false, false><<<GB, 256, 0, stream>>>(
        bufB, W3, nullptr, nullptr, nullptr, bufA, N);
    gather64<true><<<cdiv(N, 4), 256, 0, stream>>>(bufA, offsets, csr, dinv, b3, g3, be3, bufB, N);

    // ---- lin1: t = LN_ELU(h3 @ lw1 + lb1) (64->32) ----
    mfma_gemm<64, 32, true, true, false, false><<<GB, 256, 0, stream>>>(
        bufB, lw1, lb1, g4, be4, bufA, N);

    // ---- lin2: out = t @ lw2 + lb2 (32->32, fp32 out) ----
    mfma_gemm<32, 32, false, true, false, true><<<GB, 256, 0, stream>>>(
        bufA, lw2, lb2, nullptr, nullptr, out, N);
}